// Round 16
// baseline (71274.023 us; speedup 1.0000x reference)
//
#include <hip/hip_runtime.h>
#include <hip/hip_bf16.h>
#include <math.h>

#define HD 2048
#define ID 1024
#define NE 32
#define TOPK 4
#define NTOK 4096
#define NSLOT (NTOK*TOPK)

typedef __attribute__((ext_vector_type(4))) float f32x4;
typedef __attribute__((ext_vector_type(8))) short bf16x8;
typedef unsigned short u16;
typedef unsigned int u32;

union U32x4BF { uint4 u; bf16x8 h; };

static __device__ __forceinline__ u16 f2bf(float f) {
  union { float f; u32 u; } v; v.f = f;
  u32 r = v.u + 0x7fffu + ((v.u >> 16) & 1u);
  return (u16)(r >> 16);
}

static __device__ __forceinline__ u32 cvtpk(float lo, float hi) {
  u32 r;
  asm("v_cvt_pk_bf16_f32 %0, %1, %2" : "=v"(r) : "v"(lo), "v"(hi));
  return r;
}

// B direct-to-reg: 4 frags x 8 k-dwords (k = l4*8+j)
static __device__ __forceinline__ void loadBreg(const float* __restrict__ bg,
                                                const float* __restrict__ bu,
                                                u32 o0, u32 o1, u32 o2, u32 o3,
                                                u32 ldb, float bs[4][8]) {
  #pragma unroll
  for (int j = 0; j < 8; ++j) {
    bs[0][j] = bg[o0 + j*ldb];
    bs[1][j] = bu[o1 + j*ldb];
    bs[2][j] = bg[o2 + j*ldb];
    bs[3][j] = bu[o3 + j*ldb];
  }
}

static __device__ __forceinline__ void cvtB(const float bs[4][8], bf16x8 bfr[4]) {
  #pragma unroll
  for (int fn = 0; fn < 4; ++fn) {
    U32x4BF ub;
    ub.u.x = cvtpk(bs[fn][0], bs[fn][1]);
    ub.u.y = cvtpk(bs[fn][2], bs[fn][3]);
    ub.u.z = cvtpk(bs[fn][4], bs[fn][5]);
    ub.u.w = cvtpk(bs[fn][6], bs[fn][7]);
    bfr[fn] = ub.h;
  }
}

// ---------------- fused RMSNorm + residual-prefill + gate ----------------
__global__ __launch_bounds__(256) void k_prep(const float* __restrict__ x,
                                              const float* __restrict__ w,
                                              const float* __restrict__ gw,
                                              u16* __restrict__ xn,
                                              float* __restrict__ out,
                                              int* __restrict__ topk_id,
                                              float* __restrict__ topk_w,
                                              int* __restrict__ counts) {
  __shared__ float xs[HD];
  __shared__ float red[4];
  __shared__ float logits[NE];
  int t = blockIdx.x, tid = threadIdx.x;
  const float* row = x + (size_t)t*HD;
  float4 v0 = ((const float4*)row)[tid*2+0];
  float4 v1 = ((const float4*)row)[tid*2+1];
  float* orow = out + (size_t)t * HD;
  ((float4*)orow)[tid*2+0] = v0;
  ((float4*)orow)[tid*2+1] = v1;
  float ss = v0.x*v0.x+v0.y*v0.y+v0.z*v0.z+v0.w*v0.w
           + v1.x*v1.x+v1.y*v1.y+v1.z*v1.z+v1.w*v1.w;
  #pragma unroll
  for (int d=1; d<64; d<<=1) ss += __shfl_xor(ss, d);
  if ((tid&63)==0) red[tid>>6] = ss;
  __syncthreads();
  float rs = rsqrtf((red[0]+red[1]+red[2]+red[3]) * (1.0f/HD) + 1e-6f);
  const float* wp = w + tid*8;
  float a[8] = {v0.x,v0.y,v0.z,v0.w,v1.x,v1.y,v1.z,v1.w};
  float nv[8];
  #pragma unroll
  for (int j=0;j<8;++j) { nv[j] = a[j]*rs*wp[j]; xs[tid*8+j] = nv[j]; }
  uint4 o;
  o.x = (u32)f2bf(nv[0]) | ((u32)f2bf(nv[1])<<16);
  o.y = (u32)f2bf(nv[2]) | ((u32)f2bf(nv[3])<<16);
  o.z = (u32)f2bf(nv[4]) | ((u32)f2bf(nv[5])<<16);
  o.w = (u32)f2bf(nv[6]) | ((u32)f2bf(nv[7])<<16);
  ((uint4*)xn)[(size_t)t*(HD/8) + tid] = o;
  __syncthreads();
  int wave = tid>>6, lane = tid&63;
  for (int ei=0; ei<8; ++ei) {
    int e = wave*8 + ei;
    const float* g = gw + (size_t)e*HD;
    float s = 0.f;
    #pragma unroll
    for (int j=0;j<HD/64;++j) s += xs[lane + j*64] * g[lane + j*64];
    #pragma unroll
    for (int d=1; d<64; d<<=1) s += __shfl_xor(s, d);
    if (lane==0) logits[e] = s;
  }
  __syncthreads();
  if (tid==0) {
    float best[TOPK]; int bid[TOPK]; unsigned used = 0;
    for (int k2=0;k2<TOPK;++k2) {
      float bv = -1e30f; int bi = 0;
      for (int i2=0;i2<NE;++i2)
        if (!((used>>i2)&1u) && logits[i2] > bv) { bv = logits[i2]; bi = i2; }
      used |= 1u<<bi; best[k2] = bv; bid[k2] = bi;
    }
    float mx = best[0], sum = 0.f, wv[TOPK];
    for (int k2=0;k2<TOPK;++k2) { wv[k2] = expf(best[k2]-mx); sum += wv[k2]; }
    float inv = 1.f/sum;
    for (int k2=0;k2<TOPK;++k2) {
      topk_id[t*TOPK+k2] = bid[k2];
      topk_w[t*TOPK+k2] = wv[k2]*inv;
      atomicAdd(&counts[bid[k2]], 1);
    }
  }
}

__global__ void k_zero(int* counts, int* cursors) {
  int i = threadIdx.x;
  if (i < NE) { counts[i] = 0; cursors[i] = 0; }
}

__global__ void k_scan(const int* __restrict__ counts, int* __restrict__ starts) {
  if (threadIdx.x==0 && blockIdx.x==0) {
    int acc = 0;
    for (int e=0;e<NE;++e) { starts[e] = acc; acc += counts[e]; }
  }
}

__global__ __launch_bounds__(256) void k_dispatch(const int* __restrict__ topk_id,
                                                  const float* __restrict__ topk_w,
                                                  const int* __restrict__ starts,
                                                  int* __restrict__ cursors,
                                                  int* __restrict__ slot_tok,
                                                  float* __restrict__ slot_w) {
  int i = blockIdx.x*256 + threadIdx.x;
  int e = topk_id[i];
  int p = atomicAdd(&cursors[e], 1);
  int slot = starts[e] + p;
  slot_tok[slot] = i >> 2;
  slot_w[slot] = topk_w[i];
}

// ============ Fused up-GEMM + SwiGLU: barrier-free, both operands direct-to-reg ============
// 128x64 wave tile (8x4 acc). A frags: global b128 (row=fm*16+l15, k-chunk=l4), L1-shared
// across waves. B: fp32 scalar direct->reg, 2-slot pipeline. NO __syncthreads in K-loop.
__global__ __launch_bounds__(256, 2) void k_gemm_up(
    const u16* __restrict__ A, const float* __restrict__ w13,
    const float* __restrict__ sgw, const float* __restrict__ suw,
    const int* __restrict__ counts, const int* __restrict__ starts,
    const int* __restrict__ slot_tok,
    u16* __restrict__ act, u16* __restrict__ sact) {
  __shared__ int rowL[128];
  int t = threadIdx.x;
  int n0 = blockIdx.x * 128;
  int m0 = blockIdx.y * 128;
  int e  = blockIdx.z;
  bool routed = (e < NE);
  int M, rowbase;
  u16* actOut;
  if (routed) { M = counts[e]; rowbase = starts[e]; actOut = act; if (m0 >= M) return; }
  else { M = NTOK; rowbase = 0; actOut = sact; }
  if (t < 128) {
    int m = m0 + t;
    rowL[t] = routed ? slot_tok[rowbase + (m < M ? m : M-1)] : m;
  }
  __syncthreads();

  int lane = t&63, wn = t>>6;
  int l15 = lane&15, l4 = lane>>4;
  // A frag pointers: frag fm at global row rowL[fm*16+l15], k-chunk l4*8
  const u16* srcAf[8];
  #pragma unroll
  for (int fm=0; fm<8; ++fm)
    srcAf[fm] = A + (size_t)rowL[fm*16 + l15]*HD + l4*8;

  const float *bbg, *bbu;
  u32 ldb, o0, o1, o2, o3;
  {
    int c0 = n0 + (wn*2+0)*16 + l15;
    int c1 = n0 + (wn*2+1)*16 + l15;
    if (routed) {
      ldb = 2*ID;
      bbg = w13 + (size_t)e*HD*2*ID; bbu = bbg;
      u32 rb = (u32)(l4*8)*ldb;
      o0 = rb + c0; o1 = rb + c0 + ID; o2 = rb + c1; o3 = rb + c1 + ID;
    } else {
      ldb = ID;
      bbg = sgw; bbu = suw;
      u32 rb = (u32)(l4*8)*ldb;
      o0 = rb + c0; o1 = rb + c0; o2 = rb + c1; o3 = rb + c1;
    }
  }
  u32 kadv = 32*ldb;

  f32x4 acc[8][4];
  #pragma unroll
  for (int fm=0;fm<8;++fm)
    #pragma unroll
    for (int fn=0;fn<4;++fn)
      acc[fm][fn] = (f32x4){0.f,0.f,0.f,0.f};

  // prologue: B tiles 0,1 into slots A,B
  float bsA[4][8]; loadBreg(bbg, bbu, o0,o1,o2,o3, ldb, bsA);
  o0 += kadv; o1 += kadv; o2 += kadv; o3 += kadv;
  float bsB[4][8]; loadBreg(bbg, bbu, o0,o1,o2,o3, ldb, bsB);
  o0 += kadv; o1 += kadv; o2 += kadv; o3 += kadv;

  const int kiter = HD/32;
  for (int kt = 0; kt < kiter; kt += 2) {
    { // EVEN: consume bsA (tile kt); prefetch tile kt+2 into bsA
      bf16x8 af[8];
      #pragma unroll
      for (int fm=0; fm<8; ++fm) { af[fm] = *(const bf16x8*)srcAf[fm]; srcAf[fm] += 32; }
      bf16x8 bfr[4]; cvtB(bsA, bfr);
      if (kt+2 < kiter) { loadBreg(bbg, bbu, o0,o1,o2,o3, ldb, bsA);
                          o0 += kadv; o1 += kadv; o2 += kadv; o3 += kadv; }
      __builtin_amdgcn_s_setprio(1);
      #pragma unroll
      for (int fm=0; fm<8; ++fm)
        #pragma unroll
        for (int fn=0; fn<4; ++fn)
          acc[fm][fn] = __builtin_amdgcn_mfma_f32_16x16x32_bf16(af[fm], bfr[fn], acc[fm][fn], 0,0,0);
      __builtin_amdgcn_s_setprio(0);
    }
    { // ODD: consume bsB (tile kt+1); prefetch tile kt+3 into bsB
      bf16x8 af[8];
      #pragma unroll
      for (int fm=0; fm<8; ++fm) { af[fm] = *(const bf16x8*)srcAf[fm]; srcAf[fm] += 32; }
      bf16x8 bfr[4]; cvtB(bsB, bfr);
      if (kt+3 < kiter) { loadBreg(bbg, bbu, o0,o1,o2,o3, ldb, bsB);
                          o0 += kadv; o1 += kadv; o2 += kadv; o3 += kadv; }
      __builtin_amdgcn_s_setprio(1);
      #pragma unroll
      for (int fm=0; fm<8; ++fm)
        #pragma unroll
        for (int fn=0; fn<4; ++fn)
          acc[fm][fn] = __builtin_amdgcn_mfma_f32_16x16x32_bf16(af[fm], bfr[fn], acc[fm][fn], 0,0,0);
      __builtin_amdgcn_s_setprio(0);
    }
  }
  // epilogue: SwiGLU on (gate,up) fragment pairs
  #pragma unroll
  for (int fm=0; fm<8; ++fm) {
    #pragma unroll
    for (int fq=0; fq<2; ++fq) {
      f32x4 g = acc[fm][2*fq], u = acc[fm][2*fq+1];
      int col = n0 + (wn*2+fq)*16 + l15;
      #pragma unroll
      for (int r=0;r<4;++r) {
        int mloc = fm*16 + l4*4 + r;
        int m = m0 + mloc;
        if (m < M) {
          float gv = g[r];
          float av = gv / (1.f + expf(-gv)) * u[r];
          actOut[(size_t)(rowbase+m)*ID + col] = f2bf(av);
        }
      }
    }
  }
}

// ============ Fused down-GEMM: barrier-free, direct-to-reg; atomicAdd onto out ============
__global__ __launch_bounds__(256, 2) void k_gemm_down(
    const u16* __restrict__ act, const u16* __restrict__ sact,
    const float* __restrict__ w2, const float* __restrict__ sdw,
    const int* __restrict__ counts, const int* __restrict__ starts,
    const int* __restrict__ slot_tok, const float* __restrict__ slot_w,
    float* __restrict__ out) {
  __shared__ int tokL[128];
  __shared__ float wL[128];
  int t = threadIdx.x;
  int n0 = blockIdx.x * 256;
  int m0 = blockIdx.y * 128;
  int e  = blockIdx.z;
  bool routed = (e < NE);
  int M, rowbase;
  const u16* A;
  if (routed) { M = counts[e]; rowbase = starts[e]; A = act; if (m0 >= M) return; }
  else { M = NTOK; rowbase = 0; A = sact; }
  if (routed && t < 128) {
    int m = m0 + t;
    tokL[t] = (m<M) ? slot_tok[rowbase+m] : 0;
    wL[t]   = (m<M) ? slot_w[rowbase+m]  : 0.f;
  }
  if (routed) __syncthreads();

  int lane = t&63, wn = t>>6;
  int l15 = lane&15, l4 = lane>>4;
  const u16* srcAf[8];
  #pragma unroll
  for (int fm=0; fm<8; ++fm) {
    int m = m0 + fm*16 + l15;
    srcAf[fm] = A + (size_t)(rowbase + (m < M ? m : M-1))*ID + l4*8;
  }

  const float* bb = routed ? (w2 + (size_t)e*ID*HD) : sdw;
  const u32 ldb = HD;
  u32 rb = (u32)(l4*8)*ldb;
  u32 o0 = rb + n0 + wn*64 + 0*16 + l15;
  u32 o1 = rb + n0 + wn*64 + 1*16 + l15;
  u32 o2 = rb + n0 + wn*64 + 2*16 + l15;
  u32 o3 = rb + n0 + wn*64 + 3*16 + l15;
  const u32 kadv = 32*ldb;

  f32x4 acc[8][4];
  #pragma unroll
  for (int fm=0;fm<8;++fm)
    #pragma unroll
    for (int fn=0;fn<4;++fn)
      acc[fm][fn] = (f32x4){0.f,0.f,0.f,0.f};

  float bsA[4][8]; loadBreg(bb, bb, o0,o1,o2,o3, ldb, bsA);
  o0 += kadv; o1 += kadv; o2 += kadv; o3 += kadv;
  float bsB[4][8]; loadBreg(bb, bb, o0,o1,o2,o3, ldb, bsB);
  o0 += kadv; o1 += kadv; o2 += kadv; o3 += kadv;

  const int kiter = ID/32;
  for (int kt = 0; kt < kiter; kt += 2) {
    {
      bf16x8 af[8];
      #pragma unroll
      for (int fm=0; fm<8; ++fm) { af[fm] = *(const bf16x8*)srcAf[fm]; srcAf[fm] += 32; }
      bf16x8 bfr[4]; cvtB(bsA, bfr);
      if (kt+2 < kiter) { loadBreg(bb, bb, o0,o1,o2,o3, ldb, bsA);
                          o0 += kadv; o1 += kadv; o2 += kadv; o3 += kadv; }
      __builtin_amdgcn_s_setprio(1);
      #pragma unroll
      for (int fm=0; fm<8; ++fm)
        #pragma unroll
        for (int fn=0; fn<4; ++fn)
          acc[fm][fn] = __builtin_amdgcn_mfma_f32_16x16x32_bf16(af[fm], bfr[fn], acc[fm][fn], 0,0,0);
      __builtin_amdgcn_s_setprio(0);
    }
    {
      bf16x8 af[8];
      #pragma unroll
      for (int fm=0; fm<8; ++fm) { af[fm] = *(const bf16x8*)srcAf[fm]; srcAf[fm] += 32; }
      bf16x8 bfr[4]; cvtB(bsB, bfr);
      if (kt+3 < kiter) { loadBreg(bb, bb, o0,o1,o2,o3, ldb, bsB);
                          o0 += kadv; o1 += kadv; o2 += kadv; o3 += kadv; }
      __builtin_amdgcn_s_setprio(1);
      #pragma unroll
      for (int fm=0; fm<8; ++fm)
        #pragma unroll
        for (int fn=0; fn<4; ++fn)
          acc[fm][fn] = __builtin_amdgcn_mfma_f32_16x16x32_bf16(af[fm], bfr[fn], acc[fm][fn], 0,0,0);
      __builtin_amdgcn_s_setprio(0);
    }
  }
  #pragma unroll
  for (int fm=0; fm<8; ++fm) {
    #pragma unroll
    for (int fn=0; fn<4; ++fn) {
      f32x4 v = acc[fm][fn];
      int col = n0 + wn*64 + fn*16 + l15;
      #pragma unroll
      for (int r=0;r<4;++r) {
        int mloc = fm*16 + l4*4 + r;
        int m = m0 + mloc;
        if (m < M) {
          if (routed) {
            atomicAdd(&out[(size_t)tokL[mloc]*HD + col], v[r]*wL[mloc]);
          } else {
            atomicAdd(&out[(size_t)m*HD + col], v[r]);
          }
        }
      }
    }
  }
}

extern "C" void kernel_launch(void* const* d_in, const int* in_sizes, int n_in,
                              void* d_out, int out_size, void* d_ws, size_t ws_size,
                              hipStream_t stream) {
  const float* x    = (const float*)d_in[0];
  const float* nw   = (const float*)d_in[1];
  const float* gw   = (const float*)d_in[2];
  const float* w13  = (const float*)d_in[3];
  const float* w2   = (const float*)d_in[4];
  const float* sgw  = (const float*)d_in[5];
  const float* suw  = (const float*)d_in[6];
  const float* sdw  = (const float*)d_in[7];
  float* out = (float*)d_out;

  char* p = (char*)d_ws;
  u16* xn   = (u16*)p;  p += (size_t)NTOK*HD*2;
  u16* act  = (u16*)p;  p += (size_t)NSLOT*ID*2;
  u16* sact = (u16*)p;  p += (size_t)NTOK*ID*2;
  int*   topk_id  = (int*)p;   p += (size_t)NTOK*TOPK*4;
  float* topk_w   = (float*)p; p += (size_t)NTOK*TOPK*4;
  int*   slot_tok = (int*)p;   p += (size_t)NSLOT*4;
  float* slot_w   = (float*)p; p += (size_t)NSLOT*4;
  int*   counts   = (int*)p;   p += 64*4;
  int*   cursors  = (int*)p;   p += 64*4;
  int*   starts   = (int*)p;   p += 64*4;

  k_zero<<<1, 64, 0, stream>>>(counts, cursors);
  k_prep<<<NTOK, 256, 0, stream>>>(x, nw, gw, xn, out, topk_id, topk_w, counts);
  k_scan<<<1, 1, 0, stream>>>(counts, starts);
  k_dispatch<<<NSLOT/256, 256, 0, stream>>>(topk_id, topk_w, starts, cursors, slot_tok, slot_w);

  // fused up-proj + swiglu: z<NE routed experts, z==NE shared experts
  k_gemm_up<<<dim3(ID/128, 32, NE+1), 256, 0, stream>>>(
      xn, w13, sgw, suw, counts, starts, slot_tok, act, sact);
  // fused down-proj: all paths atomically accumulate onto residual-prefilled out
  k_gemm_down<<<dim3(HD/256, 32, NE+1), 256, 0, stream>>>(
      act, sact, w2, sdw, counts, starts, slot_tok, slot_w, out);
}

// Round 17
// 736.590 us; speedup vs baseline: 96.7622x; 96.7622x over previous
//
#include <hip/hip_runtime.h>
#include <hip/hip_bf16.h>
#include <math.h>

#define HD 2048
#define ID 1024
#define NE 32
#define TOPK 4
#define NTOK 4096
#define NSLOT (NTOK*TOPK)

typedef __attribute__((ext_vector_type(4))) float f32x4;
typedef __attribute__((ext_vector_type(8))) short bf16x8;
typedef unsigned short u16;
typedef unsigned int u32;

union U32x4BF { uint4 u; bf16x8 h; };

static __device__ __forceinline__ u16 f2bf(float f) {
  union { float f; u32 u; } v; v.f = f;
  u32 r = v.u + 0x7fffu + ((v.u >> 16) & 1u);
  return (u16)(r >> 16);
}

static __device__ __forceinline__ u32 cvtpk(float lo, float hi) {
  u32 r;
  asm("v_cvt_pk_bf16_f32 %0, %1, %2" : "=v"(r) : "v"(lo), "v"(hi));
  return r;
}

static __device__ __forceinline__ void barrier_lgkm() {
  asm volatile("s_waitcnt lgkmcnt(0)" ::: "memory");
  __builtin_amdgcn_s_barrier();
}

// B direct-to-reg: per lane 8 dwords per frag-column set (k = l4*8+j)
static __device__ __forceinline__ void loadBreg(const float* __restrict__ bg,
                                                const float* __restrict__ bu,
                                                u32 o0, u32 o1, u32 o2, u32 o3,
                                                u32 ldb, float bs[4][8]) {
  #pragma unroll
  for (int j = 0; j < 8; ++j) {
    bs[0][j] = bg[o0 + j*ldb];
    bs[1][j] = bu[o1 + j*ldb];
    bs[2][j] = bg[o2 + j*ldb];
    bs[3][j] = bu[o3 + j*ldb];
  }
}

static __device__ __forceinline__ void cvtB(const float bs[4][8], bf16x8 bfr[4]) {
  #pragma unroll
  for (int fn = 0; fn < 4; ++fn) {
    U32x4BF ub;
    ub.u.x = cvtpk(bs[fn][0], bs[fn][1]);
    ub.u.y = cvtpk(bs[fn][2], bs[fn][3]);
    ub.u.z = cvtpk(bs[fn][4], bs[fn][5]);
    ub.u.w = cvtpk(bs[fn][6], bs[fn][7]);
    bfr[fn] = ub.h;
  }
}

// ---------------- fused RMSNorm + residual-prefill + gate ----------------
__global__ __launch_bounds__(256) void k_prep(const float* __restrict__ x,
                                              const float* __restrict__ w,
                                              const float* __restrict__ gw,
                                              u16* __restrict__ xn,
                                              float* __restrict__ out,
                                              int* __restrict__ topk_id,
                                              float* __restrict__ topk_w,
                                              int* __restrict__ counts) {
  __shared__ float xs[HD];
  __shared__ float red[4];
  __shared__ float logits[NE];
  int t = blockIdx.x, tid = threadIdx.x;
  const float* row = x + (size_t)t*HD;
  float4 v0 = ((const float4*)row)[tid*2+0];
  float4 v1 = ((const float4*)row)[tid*2+1];
  float* orow = out + (size_t)t * HD;
  ((float4*)orow)[tid*2+0] = v0;
  ((float4*)orow)[tid*2+1] = v1;
  float ss = v0.x*v0.x+v0.y*v0.y+v0.z*v0.z+v0.w*v0.w
           + v1.x*v1.x+v1.y*v1.y+v1.z*v1.z+v1.w*v1.w;
  #pragma unroll
  for (int d=1; d<64; d<<=1) ss += __shfl_xor(ss, d);
  if ((tid&63)==0) red[tid>>6] = ss;
  __syncthreads();
  float rs = rsqrtf((red[0]+red[1]+red[2]+red[3]) * (1.0f/HD) + 1e-6f);
  const float* wp = w + tid*8;
  float a[8] = {v0.x,v0.y,v0.z,v0.w,v1.x,v1.y,v1.z,v1.w};
  float nv[8];
  #pragma unroll
  for (int j=0;j<8;++j) { nv[j] = a[j]*rs*wp[j]; xs[tid*8+j] = nv[j]; }
  uint4 o;
  o.x = (u32)f2bf(nv[0]) | ((u32)f2bf(nv[1])<<16);
  o.y = (u32)f2bf(nv[2]) | ((u32)f2bf(nv[3])<<16);
  o.z = (u32)f2bf(nv[4]) | ((u32)f2bf(nv[5])<<16);
  o.w = (u32)f2bf(nv[6]) | ((u32)f2bf(nv[7])<<16);
  ((uint4*)xn)[(size_t)t*(HD/8) + tid] = o;
  __syncthreads();
  int wave = tid>>6, lane = tid&63;
  for (int ei=0; ei<8; ++ei) {
    int e = wave*8 + ei;
    const float* g = gw + (size_t)e*HD;
    float s = 0.f;
    #pragma unroll
    for (int j=0;j<HD/64;++j) s += xs[lane + j*64] * g[lane + j*64];
    #pragma unroll
    for (int d=1; d<64; d<<=1) s += __shfl_xor(s, d);
    if (lane==0) logits[e] = s;
  }
  __syncthreads();
  if (tid==0) {
    float best[TOPK]; int bid[TOPK]; unsigned used = 0;
    for (int k2=0;k2<TOPK;++k2) {
      float bv = -1e30f; int bi = 0;
      for (int i2=0;i2<NE;++i2)
        if (!((used>>i2)&1u) && logits[i2] > bv) { bv = logits[i2]; bi = i2; }
      used |= 1u<<bi; best[k2] = bv; bid[k2] = bi;
    }
    float mx = best[0], sum = 0.f, wv[TOPK];
    for (int k2=0;k2<TOPK;++k2) { wv[k2] = expf(best[k2]-mx); sum += wv[k2]; }
    float inv = 1.f/sum;
    for (int k2=0;k2<TOPK;++k2) {
      topk_id[t*TOPK+k2] = bid[k2];
      topk_w[t*TOPK+k2] = wv[k2]*inv;
      atomicAdd(&counts[bid[k2]], 1);
    }
  }
}

__global__ void k_zero(int* counts, int* cursors) {
  int i = threadIdx.x;
  if (i < NE) { counts[i] = 0; cursors[i] = 0; }
}

__global__ void k_scan(const int* __restrict__ counts, int* __restrict__ starts) {
  if (threadIdx.x==0 && blockIdx.x==0) {
    int acc = 0;
    for (int e=0;e<NE;++e) { starts[e] = acc; acc += counts[e]; }
  }
}

__global__ __launch_bounds__(256) void k_dispatch(const int* __restrict__ topk_id,
                                                  const float* __restrict__ topk_w,
                                                  const int* __restrict__ starts,
                                                  int* __restrict__ cursors,
                                                  int* __restrict__ slot_tok,
                                                  float* __restrict__ slot_w) {
  int i = blockIdx.x*256 + threadIdx.x;
  int e = topk_id[i];
  int p = atomicAdd(&cursors[e], 1);
  int slot = starts[e] + p;
  slot_tok[slot] = i >> 2;
  slot_w[slot] = topk_w[i];
}

// ============ Fused up-GEMM + SwiGLU: z<NE routed experts, z==NE shared ============
// R10 champion: 128x64 wave tile (8x4 acc), A reg-staged -> LDS dbuf (XOR kseg, 2-way
// free), B fp32 direct->reg 2-deep named slots, lgkm-only barrier.
__global__ __launch_bounds__(256, 2) void k_gemm_up(
    const u16* __restrict__ A, const float* __restrict__ w13,
    const float* __restrict__ sgw, const float* __restrict__ suw,
    const int* __restrict__ counts, const int* __restrict__ starts,
    const int* __restrict__ slot_tok,
    u16* __restrict__ act, u16* __restrict__ sact) {
  __shared__ u16 Al[2][4096];
  __shared__ int rowL[128];
  int t = threadIdx.x;
  int n0 = blockIdx.x * 128;
  int m0 = blockIdx.y * 128;
  int e  = blockIdx.z;
  bool routed = (e < NE);
  int M, rowbase;
  u16* actOut;
  if (routed) { M = counts[e]; rowbase = starts[e]; actOut = act; if (m0 >= M) return; }
  else { M = NTOK; rowbase = 0; actOut = sact; }
  if (t < 128) {
    int m = m0 + t;
    rowL[t] = routed ? slot_tok[rowbase + (m < M ? m : M-1)] : m;
  }
  __syncthreads();
  int r0i = t>>2;
  int segA = ((t&3) ^ ((r0i>>1)&3)) << 3;
  const u16* srcA0 = A + (size_t)rowL[r0i]*HD + segA;
  const u16* srcA1 = A + (size_t)rowL[r0i+64]*HD + segA;

  int lane = t&63, wn = t>>6;
  int l15 = lane&15, l4 = lane>>4;
  int aoffb = l15*32 + ((l4 ^ ((l15>>1)&3))<<3);

  const float *bbg, *bbu;
  u32 ldb, o0, o1, o2, o3;
  {
    int c0 = n0 + (wn*2+0)*16 + l15;
    int c1 = n0 + (wn*2+1)*16 + l15;
    if (routed) {
      ldb = 2*ID;
      bbg = w13 + (size_t)e*HD*2*ID; bbu = bbg;
      u32 rb = (u32)(l4*8)*ldb;
      o0 = rb + c0; o1 = rb + c0 + ID; o2 = rb + c1; o3 = rb + c1 + ID;
    } else {
      ldb = ID;
      bbg = sgw; bbu = suw;
      u32 rb = (u32)(l4*8)*ldb;
      o0 = rb + c0; o1 = rb + c0; o2 = rb + c1; o3 = rb + c1;
    }
  }
  u32 kadv = 32*ldb;

  f32x4 acc[8][4];
  #pragma unroll
  for (int fm=0;fm<8;++fm)
    #pragma unroll
    for (int fn=0;fn<4;++fn)
      acc[fm][fn] = (f32x4){0.f,0.f,0.f,0.f};

  // prologue: tiles 0,1
  uint4 aA0 = *(const uint4*)srcA0, aA1 = *(const uint4*)srcA1;
  srcA0 += 32; srcA1 += 32;
  float bsA[4][8]; loadBreg(bbg, bbu, o0,o1,o2,o3, ldb, bsA);
  o0 += kadv; o1 += kadv; o2 += kadv; o3 += kadv;
  uint4 aB0 = *(const uint4*)srcA0, aB1 = *(const uint4*)srcA1;
  srcA0 += 32; srcA1 += 32;
  float bsB[4][8]; loadBreg(bbg, bbu, o0,o1,o2,o3, ldb, bsB);
  o0 += kadv; o1 += kadv; o2 += kadv; o3 += kadv;
  *(uint4*)&Al[0][t*8] = aA0;
  *(uint4*)&Al[0][2048 + t*8] = aA1;
  barrier_lgkm();

  const int kiter = HD/32;
  for (int kt = 0; kt < kiter; kt += 2) {
    { // EVEN: compute tile kt (Al[0], bsA); prefetch tile kt+2 into A/bsA slots
      bool pf = (kt+2 < kiter);
      if (pf) { aA0 = *(const uint4*)srcA0; aA1 = *(const uint4*)srcA1; srcA0 += 32; srcA1 += 32; }
      bf16x8 bfr[4]; cvtB(bsA, bfr);
      if (pf) { loadBreg(bbg, bbu, o0,o1,o2,o3, ldb, bsA);
                o0 += kadv; o1 += kadv; o2 += kadv; o3 += kadv; }
      __builtin_amdgcn_s_setprio(1);
      #pragma unroll
      for (int fm=0; fm<8; ++fm) {
        bf16x8 af = *(const bf16x8*)&Al[0][aoffb + fm*512];
        #pragma unroll
        for (int fn=0; fn<4; ++fn)
          acc[fm][fn] = __builtin_amdgcn_mfma_f32_16x16x32_bf16(af, bfr[fn], acc[fm][fn], 0,0,0);
      }
      __builtin_amdgcn_s_setprio(0);
      *(uint4*)&Al[1][t*8] = aB0;
      *(uint4*)&Al[1][2048 + t*8] = aB1;
      barrier_lgkm();
    }
    { // ODD: compute tile kt+1 (Al[1], bsB); prefetch tile kt+3 into B slots
      bool pf = (kt+3 < kiter);
      if (pf) { aB0 = *(const uint4*)srcA0; aB1 = *(const uint4*)srcA1; srcA0 += 32; srcA1 += 32; }
      bf16x8 bfr[4]; cvtB(bsB, bfr);
      if (pf) { loadBreg(bbg, bbu, o0,o1,o2,o3, ldb, bsB);
                o0 += kadv; o1 += kadv; o2 += kadv; o3 += kadv; }
      __builtin_amdgcn_s_setprio(1);
      #pragma unroll
      for (int fm=0; fm<8; ++fm) {
        bf16x8 af = *(const bf16x8*)&Al[1][aoffb + fm*512];
        #pragma unroll
        for (int fn=0; fn<4; ++fn)
          acc[fm][fn] = __builtin_amdgcn_mfma_f32_16x16x32_bf16(af, bfr[fn], acc[fm][fn], 0,0,0);
      }
      __builtin_amdgcn_s_setprio(0);
      if (kt+2 < kiter) {
        *(uint4*)&Al[0][t*8] = aA0;
        *(uint4*)&Al[0][2048 + t*8] = aA1;
      }
      barrier_lgkm();
    }
  }
  // epilogue: SwiGLU on (gate,up) fragment pairs
  #pragma unroll
  for (int fm=0; fm<8; ++fm) {
    #pragma unroll
    for (int fq=0; fq<2; ++fq) {
      f32x4 g = acc[fm][2*fq], u = acc[fm][2*fq+1];
      int col = n0 + (wn*2+fq)*16 + l15;
      #pragma unroll
      for (int r=0;r<4;++r) {
        int mloc = fm*16 + l4*4 + r;
        int m = m0 + mloc;
        if (m < M) {
          float gv = g[r];
          float av = gv / (1.f + expf(-gv)) * u[r];
          actOut[(size_t)(rowbase+m)*ID + col] = f2bf(av);
        }
      }
    }
  }
}

// ============ Fused down-GEMM: z<NE routed (weighted), z==NE shared; atomicAdd ============
__global__ __launch_bounds__(256, 2) void k_gemm_down(
    const u16* __restrict__ act, const u16* __restrict__ sact,
    const float* __restrict__ w2, const float* __restrict__ sdw,
    const int* __restrict__ counts, const int* __restrict__ starts,
    const int* __restrict__ slot_tok, const float* __restrict__ slot_w,
    float* __restrict__ out) {
  __shared__ u16 Al[2][4096];
  __shared__ int tokL[128];
  __shared__ float wL[128];
  int t = threadIdx.x;
  int n0 = blockIdx.x * 256;
  int m0 = blockIdx.y * 128;
  int e  = blockIdx.z;
  bool routed = (e < NE);
  int M, rowbase;
  const u16* A;
  if (routed) { M = counts[e]; rowbase = starts[e]; A = act; if (m0 >= M) return; }
  else { M = NTOK; rowbase = 0; A = sact; }
  if (routed && t < 128) {
    int m = m0 + t;
    tokL[t] = (m<M) ? slot_tok[rowbase+m] : 0;
    wL[t]   = (m<M) ? slot_w[rowbase+m]  : 0.f;
  }
  if (routed) __syncthreads();
  int r0i = t>>2;
  int segA = ((t&3) ^ ((r0i>>1)&3)) << 3;
  int am0 = m0 + r0i, am1 = m0 + r0i + 64;
  const u16* srcA0 = A + (size_t)(rowbase + (am0 < M ? am0 : M-1))*ID + segA;
  const u16* srcA1 = A + (size_t)(rowbase + (am1 < M ? am1 : M-1))*ID + segA;

  int lane = t&63, wn = t>>6;
  int l15 = lane&15, l4 = lane>>4;
  int aoffb = l15*32 + ((l4 ^ ((l15>>1)&3))<<3);

  const float* bb = routed ? (w2 + (size_t)e*ID*HD) : sdw;
  const u32 ldb = HD;
  u32 rb = (u32)(l4*8)*ldb;
  u32 o0 = rb + n0 + wn*64 + 0*16 + l15;
  u32 o1 = rb + n0 + wn*64 + 1*16 + l15;
  u32 o2 = rb + n0 + wn*64 + 2*16 + l15;
  u32 o3 = rb + n0 + wn*64 + 3*16 + l15;
  const u32 kadv = 32*ldb;

  f32x4 acc[8][4];
  #pragma unroll
  for (int fm=0;fm<8;++fm)
    #pragma unroll
    for (int fn=0;fn<4;++fn)
      acc[fm][fn] = (f32x4){0.f,0.f,0.f,0.f};

  uint4 aA0 = *(const uint4*)srcA0, aA1 = *(const uint4*)srcA1;
  srcA0 += 32; srcA1 += 32;
  float bsA[4][8]; loadBreg(bb, bb, o0,o1,o2,o3, ldb, bsA);
  o0 += kadv; o1 += kadv; o2 += kadv; o3 += kadv;
  uint4 aB0 = *(const uint4*)srcA0, aB1 = *(const uint4*)srcA1;
  srcA0 += 32; srcA1 += 32;
  float bsB[4][8]; loadBreg(bb, bb, o0,o1,o2,o3, ldb, bsB);
  o0 += kadv; o1 += kadv; o2 += kadv; o3 += kadv;
  *(uint4*)&Al[0][t*8] = aA0;
  *(uint4*)&Al[0][2048 + t*8] = aA1;
  barrier_lgkm();

  const int kiter = ID/32;
  for (int kt = 0; kt < kiter; kt += 2) {
    {
      bool pf = (kt+2 < kiter);
      if (pf) { aA0 = *(const uint4*)srcA0; aA1 = *(const uint4*)srcA1; srcA0 += 32; srcA1 += 32; }
      bf16x8 bfr[4]; cvtB(bsA, bfr);
      if (pf) { loadBreg(bb, bb, o0,o1,o2,o3, ldb, bsA);
                o0 += kadv; o1 += kadv; o2 += kadv; o3 += kadv; }
      __builtin_amdgcn_s_setprio(1);
      #pragma unroll
      for (int fm=0; fm<8; ++fm) {
        bf16x8 af = *(const bf16x8*)&Al[0][aoffb + fm*512];
        #pragma unroll
        for (int fn=0; fn<4; ++fn)
          acc[fm][fn] = __builtin_amdgcn_mfma_f32_16x16x32_bf16(af, bfr[fn], acc[fm][fn], 0,0,0);
      }
      __builtin_amdgcn_s_setprio(0);
      *(uint4*)&Al[1][t*8] = aB0;
      *(uint4*)&Al[1][2048 + t*8] = aB1;
      barrier_lgkm();
    }
    {
      bool pf = (kt+3 < kiter);
      if (pf) { aB0 = *(const uint4*)srcA0; aB1 = *(const uint4*)srcA1; srcA0 += 32; srcA1 += 32; }
      bf16x8 bfr[4]; cvtB(bsB, bfr);
      if (pf) { loadBreg(bb, bb, o0,o1,o2,o3, ldb, bsB);
                o0 += kadv; o1 += kadv; o2 += kadv; o3 += kadv; }
      __builtin_amdgcn_s_setprio(1);
      #pragma unroll
      for (int fm=0; fm<8; ++fm) {
        bf16x8 af = *(const bf16x8*)&Al[1][aoffb + fm*512];
        #pragma unroll
        for (int fn=0; fn<4; ++fn)
          acc[fm][fn] = __builtin_amdgcn_mfma_f32_16x16x32_bf16(af, bfr[fn], acc[fm][fn], 0,0,0);
      }
      __builtin_amdgcn_s_setprio(0);
      if (kt+2 < kiter) {
        *(uint4*)&Al[0][t*8] = aA0;
        *(uint4*)&Al[0][2048 + t*8] = aA1;
      }
      barrier_lgkm();
    }
  }
  #pragma unroll
  for (int fm=0; fm<8; ++fm) {
    #pragma unroll
    for (int fn=0; fn<4; ++fn) {
      f32x4 v = acc[fm][fn];
      int col = n0 + wn*64 + fn*16 + l15;
      #pragma unroll
      for (int r=0;r<4;++r) {
        int mloc = fm*16 + l4*4 + r;
        int m = m0 + mloc;
        if (m < M) {
          if (routed) {
            atomicAdd(&out[(size_t)tokL[mloc]*HD + col], v[r]*wL[mloc]);
          } else {
            atomicAdd(&out[(size_t)m*HD + col], v[r]);
          }
        }
      }
    }
  }
}

extern "C" void kernel_launch(void* const* d_in, const int* in_sizes, int n_in,
                              void* d_out, int out_size, void* d_ws, size_t ws_size,
                              hipStream_t stream) {
  const float* x    = (const float*)d_in[0];
  const float* nw   = (const float*)d_in[1];
  const float* gw   = (const float*)d_in[2];
  const float* w13  = (const float*)d_in[3];
  const float* w2   = (const float*)d_in[4];
  const float* sgw  = (const float*)d_in[5];
  const float* suw  = (const float*)d_in[6];
  const float* sdw  = (const float*)d_in[7];
  float* out = (float*)d_out;

  char* p = (char*)d_ws;
  u16* xn   = (u16*)p;  p += (size_t)NTOK*HD*2;
  u16* act  = (u16*)p;  p += (size_t)NSLOT*ID*2;
  u16* sact = (u16*)p;  p += (size_t)NTOK*ID*2;
  int*   topk_id  = (int*)p;   p += (size_t)NTOK*TOPK*4;
  float* topk_w   = (float*)p; p += (size_t)NTOK*TOPK*4;
  int*   slot_tok = (int*)p;   p += (size_t)NSLOT*4;
  float* slot_w   = (float*)p; p += (size_t)NSLOT*4;
  int*   counts   = (int*)p;   p += 64*4;
  int*   cursors  = (int*)p;   p += 64*4;
  int*   starts   = (int*)p;   p += 64*4;

  k_zero<<<1, 64, 0, stream>>>(counts, cursors);
  k_prep<<<NTOK, 256, 0, stream>>>(x, nw, gw, xn, out, topk_id, topk_w, counts);
  k_scan<<<1, 1, 0, stream>>>(counts, starts);
  k_dispatch<<<NSLOT/256, 256, 0, stream>>>(topk_id, topk_w, starts, cursors, slot_tok, slot_w);

  // fused up-proj + swiglu: z<NE routed experts, z==NE shared experts
  k_gemm_up<<<dim3(ID/128, 32, NE+1), 256, 0, stream>>>(
      xn, w13, sgw, suw, counts, starts, slot_tok, act, sact);
  // fused down-proj: all paths atomically accumulate onto residual-prefilled out
  k_gemm_down<<<dim3(HD/256, 32, NE+1), 256, 0, stream>>>(
      act, sact, w2, sdw, counts, starts, slot_tok, slot_w, out);
}

// Round 18
// 726.186 us; speedup vs baseline: 98.1485x; 1.0143x over previous
//
#include <hip/hip_runtime.h>
#include <hip/hip_bf16.h>
#include <math.h>

#define HD 2048
#define ID 1024
#define NE 32
#define TOPK 4
#define NTOK 4096
#define NSLOT (NTOK*TOPK)
#define MAXTILE 192

typedef __attribute__((ext_vector_type(4))) float f32x4;
typedef __attribute__((ext_vector_type(8))) short bf16x8;
typedef unsigned short u16;
typedef unsigned int u32;

union U32x4BF { uint4 u; bf16x8 h; };

static __device__ __forceinline__ u16 f2bf(float f) {
  union { float f; u32 u; } v; v.f = f;
  u32 r = v.u + 0x7fffu + ((v.u >> 16) & 1u);
  return (u16)(r >> 16);
}

static __device__ __forceinline__ u32 cvtpk(float lo, float hi) {
  u32 r;
  asm("v_cvt_pk_bf16_f32 %0, %1, %2" : "=v"(r) : "v"(lo), "v"(hi));
  return r;
}

static __device__ __forceinline__ void barrier_lgkm() {
  asm volatile("s_waitcnt lgkmcnt(0)" ::: "memory");
  __builtin_amdgcn_s_barrier();
}

// B direct-to-reg: per lane 8 dwords per frag-column set (k = l4*8+j)
static __device__ __forceinline__ void loadBreg(const float* __restrict__ bg,
                                                const float* __restrict__ bu,
                                                u32 o0, u32 o1, u32 o2, u32 o3,
                                                u32 ldb, float bs[4][8]) {
  #pragma unroll
  for (int j = 0; j < 8; ++j) {
    bs[0][j] = bg[o0 + j*ldb];
    bs[1][j] = bu[o1 + j*ldb];
    bs[2][j] = bg[o2 + j*ldb];
    bs[3][j] = bu[o3 + j*ldb];
  }
}

static __device__ __forceinline__ void cvtB(const float bs[4][8], bf16x8 bfr[4]) {
  #pragma unroll
  for (int fn = 0; fn < 4; ++fn) {
    U32x4BF ub;
    ub.u.x = cvtpk(bs[fn][0], bs[fn][1]);
    ub.u.y = cvtpk(bs[fn][2], bs[fn][3]);
    ub.u.z = cvtpk(bs[fn][4], bs[fn][5]);
    ub.u.w = cvtpk(bs[fn][6], bs[fn][7]);
    bfr[fn] = ub.h;
  }
}

// ---------------- fused RMSNorm + residual-prefill + gate ----------------
__global__ __launch_bounds__(256) void k_prep(const float* __restrict__ x,
                                              const float* __restrict__ w,
                                              const float* __restrict__ gw,
                                              u16* __restrict__ xn,
                                              float* __restrict__ out,
                                              int* __restrict__ topk_id,
                                              float* __restrict__ topk_w,
                                              int* __restrict__ counts) {
  __shared__ float xs[HD];
  __shared__ float red[4];
  __shared__ float logits[NE];
  int t = blockIdx.x, tid = threadIdx.x;
  const float* row = x + (size_t)t*HD;
  float4 v0 = ((const float4*)row)[tid*2+0];
  float4 v1 = ((const float4*)row)[tid*2+1];
  float* orow = out + (size_t)t * HD;
  ((float4*)orow)[tid*2+0] = v0;
  ((float4*)orow)[tid*2+1] = v1;
  float ss = v0.x*v0.x+v0.y*v0.y+v0.z*v0.z+v0.w*v0.w
           + v1.x*v1.x+v1.y*v1.y+v1.z*v1.z+v1.w*v1.w;
  #pragma unroll
  for (int d=1; d<64; d<<=1) ss += __shfl_xor(ss, d);
  if ((tid&63)==0) red[tid>>6] = ss;
  __syncthreads();
  float rs = rsqrtf((red[0]+red[1]+red[2]+red[3]) * (1.0f/HD) + 1e-6f);
  const float* wp = w + tid*8;
  float a[8] = {v0.x,v0.y,v0.z,v0.w,v1.x,v1.y,v1.z,v1.w};
  float nv[8];
  #pragma unroll
  for (int j=0;j<8;++j) { nv[j] = a[j]*rs*wp[j]; xs[tid*8+j] = nv[j]; }
  uint4 o;
  o.x = (u32)f2bf(nv[0]) | ((u32)f2bf(nv[1])<<16);
  o.y = (u32)f2bf(nv[2]) | ((u32)f2bf(nv[3])<<16);
  o.z = (u32)f2bf(nv[4]) | ((u32)f2bf(nv[5])<<16);
  o.w = (u32)f2bf(nv[6]) | ((u32)f2bf(nv[7])<<16);
  ((uint4*)xn)[(size_t)t*(HD/8) + tid] = o;
  __syncthreads();
  int wave = tid>>6, lane = tid&63;
  for (int ei=0; ei<8; ++ei) {
    int e = wave*8 + ei;
    const float* g = gw + (size_t)e*HD;
    float s = 0.f;
    #pragma unroll
    for (int j=0;j<HD/64;++j) s += xs[lane + j*64] * g[lane + j*64];
    #pragma unroll
    for (int d=1; d<64; d<<=1) s += __shfl_xor(s, d);
    if (lane==0) logits[e] = s;
  }
  __syncthreads();
  if (tid==0) {
    float best[TOPK]; int bid[TOPK]; unsigned used = 0;
    for (int k2=0;k2<TOPK;++k2) {
      float bv = -1e30f; int bi = 0;
      for (int i2=0;i2<NE;++i2)
        if (!((used>>i2)&1u) && logits[i2] > bv) { bv = logits[i2]; bi = i2; }
      used |= 1u<<bi; best[k2] = bv; bid[k2] = bi;
    }
    float mx = best[0], sum = 0.f, wv[TOPK];
    for (int k2=0;k2<TOPK;++k2) { wv[k2] = expf(best[k2]-mx); sum += wv[k2]; }
    float inv = 1.f/sum;
    for (int k2=0;k2<TOPK;++k2) {
      topk_id[t*TOPK+k2] = bid[k2];
      topk_w[t*TOPK+k2] = wv[k2]*inv;
      atomicAdd(&counts[bid[k2]], 1);
    }
  }
}

__global__ void k_zero(int* counts, int* cursors) {
  int i = threadIdx.x;
  if (i < NE) { counts[i] = 0; cursors[i] = 0; }
}

// starts + compact m-tile map (tiles only where rows exist)
__global__ void k_scan(const int* __restrict__ counts, int* __restrict__ starts,
                       int* __restrict__ tile_e, int* __restrict__ tile_m0,
                       int* __restrict__ ntile) {
  if (threadIdx.x==0 && blockIdx.x==0) {
    int acc = 0;
    for (int e=0;e<NE;++e) { starts[e] = acc; acc += counts[e]; }
    int nt = 0;
    for (int e=0;e<NE;++e)
      for (int m0=0; m0<counts[e] && nt<MAXTILE; m0+=128) {
        tile_e[nt] = e; tile_m0[nt] = m0; ++nt;
      }
    ntile[0] = nt;
  }
}

__global__ __launch_bounds__(256) void k_dispatch(const int* __restrict__ topk_id,
                                                  const float* __restrict__ topk_w,
                                                  const int* __restrict__ starts,
                                                  int* __restrict__ cursors,
                                                  int* __restrict__ slot_tok,
                                                  float* __restrict__ slot_w) {
  int i = blockIdx.x*256 + threadIdx.x;
  int e = topk_id[i];
  int p = atomicAdd(&cursors[e], 1);
  int slot = starts[e] + p;
  slot_tok[slot] = i >> 2;
  slot_w[slot] = topk_w[i];
}

// ============ Fused up-GEMM + SwiGLU (R17 inner loop; tile-map scheduling) ============
// grid y: [0,32) shared-expert m-tiles (dispatch first), [32,32+MAXTILE) routed tile map.
__global__ __launch_bounds__(256, 2) void k_gemm_up(
    const u16* __restrict__ A, const float* __restrict__ w13,
    const float* __restrict__ sgw, const float* __restrict__ suw,
    const int* __restrict__ counts, const int* __restrict__ starts,
    const int* __restrict__ slot_tok,
    const int* __restrict__ tile_e, const int* __restrict__ tile_m0,
    const int* __restrict__ ntile,
    u16* __restrict__ act, u16* __restrict__ sact) {
  __shared__ u16 Al[2][4096];
  __shared__ int rowL[128];
  int t = threadIdx.x;
  int n0 = blockIdx.x * 128;
  int ty = blockIdx.y;
  bool routed = (ty >= 32);
  int e, m0, M, rowbase;
  u16* actOut;
  if (routed) {
    int idx = ty - 32;
    if (idx >= ntile[0]) return;
    e = tile_e[idx]; m0 = tile_m0[idx];
    M = counts[e]; rowbase = starts[e]; actOut = act;
  } else {
    e = NE; m0 = ty * 128; M = NTOK; rowbase = 0; actOut = sact;
  }
  if (t < 128) {
    int m = m0 + t;
    rowL[t] = routed ? slot_tok[rowbase + (m < M ? m : M-1)] : m;
  }
  __syncthreads();
  int r0i = t>>2;
  int segA = ((t&3) ^ ((r0i>>1)&3)) << 3;
  const u16* srcA0 = A + (size_t)rowL[r0i]*HD + segA;
  const u16* srcA1 = A + (size_t)rowL[r0i+64]*HD + segA;

  int lane = t&63, wn = t>>6;
  int l15 = lane&15, l4 = lane>>4;
  int aoffb = l15*32 + ((l4 ^ ((l15>>1)&3))<<3);

  const float *bbg, *bbu;
  u32 ldb, o0, o1, o2, o3;
  {
    int c0 = n0 + (wn*2+0)*16 + l15;
    int c1 = n0 + (wn*2+1)*16 + l15;
    if (routed) {
      ldb = 2*ID;
      bbg = w13 + (size_t)e*HD*2*ID; bbu = bbg;
      u32 rb = (u32)(l4*8)*ldb;
      o0 = rb + c0; o1 = rb + c0 + ID; o2 = rb + c1; o3 = rb + c1 + ID;
    } else {
      ldb = ID;
      bbg = sgw; bbu = suw;
      u32 rb = (u32)(l4*8)*ldb;
      o0 = rb + c0; o1 = rb + c0; o2 = rb + c1; o3 = rb + c1;
    }
  }
  u32 kadv = 32*ldb;

  f32x4 acc[8][4];
  #pragma unroll
  for (int fm=0;fm<8;++fm)
    #pragma unroll
    for (int fn=0;fn<4;++fn)
      acc[fm][fn] = (f32x4){0.f,0.f,0.f,0.f};

  // prologue: tiles 0,1
  uint4 aA0 = *(const uint4*)srcA0, aA1 = *(const uint4*)srcA1;
  srcA0 += 32; srcA1 += 32;
  float bsA[4][8]; loadBreg(bbg, bbu, o0,o1,o2,o3, ldb, bsA);
  o0 += kadv; o1 += kadv; o2 += kadv; o3 += kadv;
  uint4 aB0 = *(const uint4*)srcA0, aB1 = *(const uint4*)srcA1;
  srcA0 += 32; srcA1 += 32;
  float bsB[4][8]; loadBreg(bbg, bbu, o0,o1,o2,o3, ldb, bsB);
  o0 += kadv; o1 += kadv; o2 += kadv; o3 += kadv;
  *(uint4*)&Al[0][t*8] = aA0;
  *(uint4*)&Al[0][2048 + t*8] = aA1;
  barrier_lgkm();

  const int kiter = HD/32;
  for (int kt = 0; kt < kiter; kt += 2) {
    { // EVEN
      bool pf = (kt+2 < kiter);
      if (pf) { aA0 = *(const uint4*)srcA0; aA1 = *(const uint4*)srcA1; srcA0 += 32; srcA1 += 32; }
      bf16x8 bfr[4]; cvtB(bsA, bfr);
      if (pf) { loadBreg(bbg, bbu, o0,o1,o2,o3, ldb, bsA);
                o0 += kadv; o1 += kadv; o2 += kadv; o3 += kadv; }
      __builtin_amdgcn_s_setprio(1);
      #pragma unroll
      for (int fm=0; fm<8; ++fm) {
        bf16x8 af = *(const bf16x8*)&Al[0][aoffb + fm*512];
        #pragma unroll
        for (int fn=0; fn<4; ++fn)
          acc[fm][fn] = __builtin_amdgcn_mfma_f32_16x16x32_bf16(af, bfr[fn], acc[fm][fn], 0,0,0);
      }
      __builtin_amdgcn_s_setprio(0);
      *(uint4*)&Al[1][t*8] = aB0;
      *(uint4*)&Al[1][2048 + t*8] = aB1;
      barrier_lgkm();
    }
    { // ODD
      bool pf = (kt+3 < kiter);
      if (pf) { aB0 = *(const uint4*)srcA0; aB1 = *(const uint4*)srcA1; srcA0 += 32; srcA1 += 32; }
      bf16x8 bfr[4]; cvtB(bsB, bfr);
      if (pf) { loadBreg(bbg, bbu, o0,o1,o2,o3, ldb, bsB);
                o0 += kadv; o1 += kadv; o2 += kadv; o3 += kadv; }
      __builtin_amdgcn_s_setprio(1);
      #pragma unroll
      for (int fm=0; fm<8; ++fm) {
        bf16x8 af = *(const bf16x8*)&Al[1][aoffb + fm*512];
        #pragma unroll
        for (int fn=0; fn<4; ++fn)
          acc[fm][fn] = __builtin_amdgcn_mfma_f32_16x16x32_bf16(af, bfr[fn], acc[fm][fn], 0,0,0);
      }
      __builtin_amdgcn_s_setprio(0);
      if (kt+2 < kiter) {
        *(uint4*)&Al[0][t*8] = aA0;
        *(uint4*)&Al[0][2048 + t*8] = aA1;
      }
      barrier_lgkm();
    }
  }
  // epilogue: SwiGLU
  #pragma unroll
  for (int fm=0; fm<8; ++fm) {
    #pragma unroll
    for (int fq=0; fq<2; ++fq) {
      f32x4 g = acc[fm][2*fq], u = acc[fm][2*fq+1];
      int col = n0 + (wn*2+fq)*16 + l15;
      #pragma unroll
      for (int r=0;r<4;++r) {
        int mloc = fm*16 + l4*4 + r;
        int m = m0 + mloc;
        if (m < M) {
          float gv = g[r];
          float av = gv / (1.f + expf(-gv)) * u[r];
          actOut[(size_t)(rowbase+m)*ID + col] = f2bf(av);
        }
      }
    }
  }
}

// ============ Fused down-GEMM (R17 inner loop; tile-map scheduling) ============
__global__ __launch_bounds__(256, 2) void k_gemm_down(
    const u16* __restrict__ act, const u16* __restrict__ sact,
    const float* __restrict__ w2, const float* __restrict__ sdw,
    const int* __restrict__ counts, const int* __restrict__ starts,
    const int* __restrict__ slot_tok, const float* __restrict__ slot_w,
    const int* __restrict__ tile_e, const int* __restrict__ tile_m0,
    const int* __restrict__ ntile,
    float* __restrict__ out) {
  __shared__ u16 Al[2][4096];
  __shared__ int tokL[128];
  __shared__ float wL[128];
  int t = threadIdx.x;
  int n0 = blockIdx.x * 256;
  int ty = blockIdx.y;
  bool routed = (ty >= 32);
  int e, m0, M, rowbase;
  const u16* A;
  if (routed) {
    int idx = ty - 32;
    if (idx >= ntile[0]) return;
    e = tile_e[idx]; m0 = tile_m0[idx];
    M = counts[e]; rowbase = starts[e]; A = act;
  } else {
    e = NE; m0 = ty * 128; M = NTOK; rowbase = 0; A = sact;
  }
  if (routed && t < 128) {
    int m = m0 + t;
    tokL[t] = (m<M) ? slot_tok[rowbase+m] : 0;
    wL[t]   = (m<M) ? slot_w[rowbase+m]  : 0.f;
  }
  if (routed) __syncthreads();
  int r0i = t>>2;
  int segA = ((t&3) ^ ((r0i>>1)&3)) << 3;
  int am0 = m0 + r0i, am1 = m0 + r0i + 64;
  const u16* srcA0 = A + (size_t)(rowbase + (am0 < M ? am0 : M-1))*ID + segA;
  const u16* srcA1 = A + (size_t)(rowbase + (am1 < M ? am1 : M-1))*ID + segA;

  int lane = t&63, wn = t>>6;
  int l15 = lane&15, l4 = lane>>4;
  int aoffb = l15*32 + ((l4 ^ ((l15>>1)&3))<<3);

  const float* bb = routed ? (w2 + (size_t)e*ID*HD) : sdw;
  const u32 ldb = HD;
  u32 rb = (u32)(l4*8)*ldb;
  u32 o0 = rb + n0 + wn*64 + 0*16 + l15;
  u32 o1 = rb + n0 + wn*64 + 1*16 + l15;
  u32 o2 = rb + n0 + wn*64 + 2*16 + l15;
  u32 o3 = rb + n0 + wn*64 + 3*16 + l15;
  const u32 kadv = 32*ldb;

  f32x4 acc[8][4];
  #pragma unroll
  for (int fm=0;fm<8;++fm)
    #pragma unroll
    for (int fn=0;fn<4;++fn)
      acc[fm][fn] = (f32x4){0.f,0.f,0.f,0.f};

  uint4 aA0 = *(const uint4*)srcA0, aA1 = *(const uint4*)srcA1;
  srcA0 += 32; srcA1 += 32;
  float bsA[4][8]; loadBreg(bb, bb, o0,o1,o2,o3, ldb, bsA);
  o0 += kadv; o1 += kadv; o2 += kadv; o3 += kadv;
  uint4 aB0 = *(const uint4*)srcA0, aB1 = *(const uint4*)srcA1;
  srcA0 += 32; srcA1 += 32;
  float bsB[4][8]; loadBreg(bb, bb, o0,o1,o2,o3, ldb, bsB);
  o0 += kadv; o1 += kadv; o2 += kadv; o3 += kadv;
  *(uint4*)&Al[0][t*8] = aA0;
  *(uint4*)&Al[0][2048 + t*8] = aA1;
  barrier_lgkm();

  const int kiter = ID/32;
  for (int kt = 0; kt < kiter; kt += 2) {
    {
      bool pf = (kt+2 < kiter);
      if (pf) { aA0 = *(const uint4*)srcA0; aA1 = *(const uint4*)srcA1; srcA0 += 32; srcA1 += 32; }
      bf16x8 bfr[4]; cvtB(bsA, bfr);
      if (pf) { loadBreg(bb, bb, o0,o1,o2,o3, ldb, bsA);
                o0 += kadv; o1 += kadv; o2 += kadv; o3 += kadv; }
      __builtin_amdgcn_s_setprio(1);
      #pragma unroll
      for (int fm=0; fm<8; ++fm) {
        bf16x8 af = *(const bf16x8*)&Al[0][aoffb + fm*512];
        #pragma unroll
        for (int fn=0; fn<4; ++fn)
          acc[fm][fn] = __builtin_amdgcn_mfma_f32_16x16x32_bf16(af, bfr[fn], acc[fm][fn], 0,0,0);
      }
      __builtin_amdgcn_s_setprio(0);
      *(uint4*)&Al[1][t*8] = aB0;
      *(uint4*)&Al[1][2048 + t*8] = aB1;
      barrier_lgkm();
    }
    {
      bool pf = (kt+3 < kiter);
      if (pf) { aB0 = *(const uint4*)srcA0; aB1 = *(const uint4*)srcA1; srcA0 += 32; srcA1 += 32; }
      bf16x8 bfr[4]; cvtB(bsB, bfr);
      if (pf) { loadBreg(bb, bb, o0,o1,o2,o3, ldb, bsB);
                o0 += kadv; o1 += kadv; o2 += kadv; o3 += kadv; }
      __builtin_amdgcn_s_setprio(1);
      #pragma unroll
      for (int fm=0; fm<8; ++fm) {
        bf16x8 af = *(const bf16x8*)&Al[1][aoffb + fm*512];
        #pragma unroll
        for (int fn=0; fn<4; ++fn)
          acc[fm][fn] = __builtin_amdgcn_mfma_f32_16x16x32_bf16(af, bfr[fn], acc[fm][fn], 0,0,0);
      }
      __builtin_amdgcn_s_setprio(0);
      if (kt+2 < kiter) {
        *(uint4*)&Al[0][t*8] = aA0;
        *(uint4*)&Al[0][2048 + t*8] = aA1;
      }
      barrier_lgkm();
    }
  }
  #pragma unroll
  for (int fm=0; fm<8; ++fm) {
    #pragma unroll
    for (int fn=0; fn<4; ++fn) {
      f32x4 v = acc[fm][fn];
      int col = n0 + wn*64 + fn*16 + l15;
      #pragma unroll
      for (int r=0;r<4;++r) {
        int mloc = fm*16 + l4*4 + r;
        int m = m0 + mloc;
        if (m < M) {
          if (routed) {
            atomicAdd(&out[(size_t)tokL[mloc]*HD + col], v[r]*wL[mloc]);
          } else {
            atomicAdd(&out[(size_t)m*HD + col], v[r]);
          }
        }
      }
    }
  }
}

extern "C" void kernel_launch(void* const* d_in, const int* in_sizes, int n_in,
                              void* d_out, int out_size, void* d_ws, size_t ws_size,
                              hipStream_t stream) {
  const float* x    = (const float*)d_in[0];
  const float* nw   = (const float*)d_in[1];
  const float* gw   = (const float*)d_in[2];
  const float* w13  = (const float*)d_in[3];
  const float* w2   = (const float*)d_in[4];
  const float* sgw  = (const float*)d_in[5];
  const float* suw  = (const float*)d_in[6];
  const float* sdw  = (const float*)d_in[7];
  float* out = (float*)d_out;

  char* p = (char*)d_ws;
  u16* xn   = (u16*)p;  p += (size_t)NTOK*HD*2;
  u16* act  = (u16*)p;  p += (size_t)NSLOT*ID*2;
  u16* sact = (u16*)p;  p += (size_t)NTOK*ID*2;
  int*   topk_id  = (int*)p;   p += (size_t)NTOK*TOPK*4;
  float* topk_w   = (float*)p; p += (size_t)NTOK*TOPK*4;
  int*   slot_tok = (int*)p;   p += (size_t)NSLOT*4;
  float* slot_w   = (float*)p; p += (size_t)NSLOT*4;
  int*   counts   = (int*)p;   p += 64*4;
  int*   cursors  = (int*)p;   p += 64*4;
  int*   starts   = (int*)p;   p += 64*4;
  int*   tile_e   = (int*)p;   p += MAXTILE*4;
  int*   tile_m0  = (int*)p;   p += MAXTILE*4;
  int*   ntile    = (int*)p;   p += 64*4;

  k_zero<<<1, 64, 0, stream>>>(counts, cursors);
  k_prep<<<NTOK, 256, 0, stream>>>(x, nw, gw, xn, out, topk_id, topk_w, counts);
  k_scan<<<1, 1, 0, stream>>>(counts, starts, tile_e, tile_m0, ntile);
  k_dispatch<<<NSLOT/256, 256, 0, stream>>>(topk_id, topk_w, starts, cursors, slot_tok, slot_w);

  // fused up-proj + swiglu: y<32 shared (dispatch first), y>=32 routed tile map
  k_gemm_up<<<dim3(ID/128, 32 + MAXTILE, 1), 256, 0, stream>>>(
      xn, w13, sgw, suw, counts, starts, slot_tok, tile_e, tile_m0, ntile, act, sact);
  // fused down-proj
  k_gemm_down<<<dim3(HD/256, 32 + MAXTILE, 1), 256, 0, stream>>>(
      act, sact, w2, sdw, counts, starts, slot_tok, slot_w, tile_e, tile_m0, ntile, out);
}